// Round 5
// baseline (536.345 us; speedup 1.0000x reference)
//
#include <hip/hip_runtime.h>

#define N_V  20000
#define B_   8
#define F_   64
#define K_   6
#define OUT_ 64
#define NNZ_ 320000
#define BF   512    // B_*F_
#define NSLICE 8
#define SLICE_W 2500
#define NBUK (N_V * NSLICE)        // 160000 buckets
#define SCANB 157                  // ceil(NBUK/1024)

typedef unsigned short ushort_t;
typedef unsigned int   uint_t;

using frag_ab = __attribute__((ext_vector_type(8))) short;  // 8 bf16 (4 VGPRs)
using frag_cd = __attribute__((ext_vector_type(4))) float;  // 4 f32 acc

// ---- bf16 helpers ----
__device__ __forceinline__ ushort_t f2bf(float f) {          // round-to-nearest-even
    uint_t u = __float_as_uint(f);
    u += 0x7FFFu + ((u >> 16) & 1u);
    return (ushort_t)(u >> 16);
}
__device__ __forceinline__ uint_t pack2(float lo, float hi) {
    return (uint_t)f2bf(lo) | ((uint_t)f2bf(hi) << 16);
}
__device__ __forceinline__ void unpack2(uint_t u, float& lo, float& hi) {
    lo = __uint_as_float(u << 16);
    hi = __uint_as_float(u & 0xFFFF0000u);
}
__device__ __forceinline__ void unpack4(uint2 u, float* e) {
    unpack2(u.x, e[0], e[1]); unpack2(u.y, e[2], e[3]);
}

// ---------------- bucketed CSR build: key = row*8 + col/2500 ----------------

__global__ void hist_kernel(const int* __restrict__ rows, const int* __restrict__ cols,
                            int* __restrict__ counts) {
    int e = blockIdx.x * 256 + threadIdx.x;
    if (e < NNZ_) {
        int key = rows[e] * NSLICE + cols[e] / SLICE_W;
        atomicAdd(&counts[key], 1);
    }
}

__global__ __launch_bounds__(1024) void scan1(const int* __restrict__ counts,
                                              int* __restrict__ incl, int* __restrict__ bsum) {
    __shared__ int buf[1024];
    int tid = threadIdx.x;
    int i = blockIdx.x * 1024 + tid;
    int c = (i < NBUK) ? counts[i] : 0;
    buf[tid] = c;
    __syncthreads();
    for (int off = 1; off < 1024; off <<= 1) {
        int t = buf[tid];
        int add = (tid >= off) ? buf[tid - off] : 0;
        __syncthreads();
        buf[tid] = t + add;
        __syncthreads();
    }
    if (i < NBUK) incl[i] = buf[tid];
    if (tid == 1023) bsum[blockIdx.x] = buf[1023];
}

__global__ __launch_bounds__(256) void scan2(int* __restrict__ bsum) {
    __shared__ int buf[256];
    int tid = threadIdx.x;
    int c = (tid < SCANB) ? bsum[tid] : 0;
    buf[tid] = c;
    __syncthreads();
    for (int off = 1; off < 256; off <<= 1) {
        int t = buf[tid];
        int add = (tid >= off) ? buf[tid - off] : 0;
        __syncthreads();
        buf[tid] = t + add;
        __syncthreads();
    }
    if (tid < SCANB) bsum[tid] = buf[tid] - c;   // exclusive block offsets
}

__global__ __launch_bounds__(1024) void scan3(const int* __restrict__ counts,
                                              const int* __restrict__ bsum,
                                              int* __restrict__ bp, int* __restrict__ cursor) {
    int tid = threadIdx.x;
    int i = blockIdx.x * 1024 + tid;
    if (i < NBUK) {
        int p = bsum[blockIdx.x] + cursor[i];   // global inclusive prefix
        bp[i + 1] = p;
        cursor[i] = p - counts[i];              // bucket start for scatter
    }
    if (i == 0) bp[0] = 0;
}

// edges packed: {col, val_bits}
__global__ void scatter_kernel(const int* __restrict__ rows, const int* __restrict__ cols,
                               const float* __restrict__ vals, int* __restrict__ cursor,
                               int2* __restrict__ edges) {
    int e = blockIdx.x * 256 + threadIdx.x;
    if (e < NNZ_) {
        int c = cols[e];
        int key = rows[e] * NSLICE + c / SLICE_W;
        int pos = atomicAdd(&cursor[key], 1);
        int2 pe; pe.x = c; pe.y = __float_as_int(vals[e]);
        edges[pos] = pe;
    }
}

// ---------------- fat prep: x->X0 bf16 (T layout) + Wfrag pack ----------------
__global__ void prep_kernel(const float* __restrict__ x, uint_t* __restrict__ X0,
                            const float* __restrict__ W, ushort_t* __restrict__ Wfrag) {
    int blk = blockIdx.x;
    if (blk < 20000) {
        int idx = blk * 256 + threadIdx.x;      // over N_V*B_*32
        int f2 = idx & 31;
        int b  = (idx >> 5) & 7;
        int n  = idx >> 8;
        float2 v = *(const float2*)&x[((size_t)b * N_V + n) * F_ + f2 * 2];
        X0[n * 256 + b * 32 + f2] = pack2(v.x, v.y);
    } else {
        int idx = (blk - 20000) * 256 + threadIdx.x;
        if (idx < 12 * 4 * 64 * 8) {
            int j    = idx & 7;
            int lane = (idx >> 3) & 63;
            int ct   = (idx >> 9) & 3;
            int s    = idx >> 11;
            int o     = ct * 16 + (lane & 15);
            int kglob = s * 32 + ((lane >> 4) & 3) * 8 + j;
            Wfrag[idx] = f2bf(W[o * (K_ * F_) + kglob]);
        }
    }
}

// ---------------- column-phased SpMM, feature-split waves ----------------
// Block = 4 waves. wave>>1 selects row group (4 rows), wave&1 selects feature half
// (256 bf16). Lane owns 4 bf16 (uint2 gather). Row-pair lockstep: 4 gathers in flight.
template <bool RECUR>
__global__ __launch_bounds__(256) void cheb_phase(const int* __restrict__ bp,
                                                  const int2* __restrict__ edges,
                                                  const ushort_t* __restrict__ Tprev,
                                                  const ushort_t* __restrict__ Tpp,
                                                  ushort_t* __restrict__ Tout) {
    const int wave = threadIdx.x >> 6, lane = threadIdx.x & 63;
    const int half = wave & 1;
    const int n0 = blockIdx.x * 8 + (wave >> 1) * 4;
    const int fo = half * 256 + lane * 4;          // bf16 offset within 512-row

    // preload bucket bounds for the wave's 4 rows (contiguous: key = row*8+s)
    int bpr[4][9];
#pragma unroll
    for (int r = 0; r < 4; ++r) {
        const int4 a = *(const int4*)&bp[(n0 + r) * 8];
        const int4 b = *(const int4*)&bp[(n0 + r) * 8 + 4];
        bpr[r][0] = a.x; bpr[r][1] = a.y; bpr[r][2] = a.z; bpr[r][3] = a.w;
        bpr[r][4] = b.x; bpr[r][5] = b.y; bpr[r][6] = b.z; bpr[r][7] = b.w;
        bpr[r][8] = bp[(n0 + r) * 8 + 8];
    }

    float acc[4][4];
#pragma unroll
    for (int r = 0; r < 4; ++r)
#pragma unroll
        for (int i = 0; i < 4; ++i) acc[r][i] = 0.f;

    for (int s = 0; s < NSLICE; ++s) {
#pragma unroll
        for (int rp = 0; rp < 2; ++rp) {
            const int r0 = rp * 2, r1 = rp * 2 + 1;
            const int s0 = bpr[r0][s], e0n = bpr[r0][s + 1];
            const int s1 = bpr[r1][s], e1n = bpr[r1][s + 1];
            const int d0 = e0n - s0, d1 = e1n - s1;
            const int mx = d0 > d1 ? d0 : d1;
            for (int t = 0; t < mx; t += 2) {
                int ja = s0 + t, jb = ja + 1;
                int ka = s1 + t, kb = ka + 1;
                int2 ea = edges[max(min(ja, e0n - 1), 0)];
                int2 eb = edges[max(min(jb, e0n - 1), 0)];
                int2 ec = edges[max(min(ka, e1n - 1), 0)];
                int2 ed = edges[max(min(kb, e1n - 1), 0)];
                float va = (ja < e0n) ? __int_as_float(ea.y) : 0.f;
                float vb = (jb < e0n) ? __int_as_float(eb.y) : 0.f;
                float vc = (ka < e1n) ? __int_as_float(ec.y) : 0.f;
                float vd = (kb < e1n) ? __int_as_float(ed.y) : 0.f;
                uint2 ua = *(const uint2*)(Tprev + (size_t)ea.x * BF + fo);
                uint2 ub = *(const uint2*)(Tprev + (size_t)eb.x * BF + fo);
                uint2 uc = *(const uint2*)(Tprev + (size_t)ec.x * BF + fo);
                uint2 ud = *(const uint2*)(Tprev + (size_t)ed.x * BF + fo);
                float xa[4], xb[4], xc[4], xd[4];
                unpack4(ua, xa); unpack4(ub, xb);
                unpack4(uc, xc); unpack4(ud, xd);
#pragma unroll
                for (int i = 0; i < 4; ++i) {
                    acc[r0][i] = fmaf(va, xa[i], acc[r0][i]);
                    acc[r0][i] = fmaf(vb, xb[i], acc[r0][i]);
                    acc[r1][i] = fmaf(vc, xc[i], acc[r1][i]);
                    acc[r1][i] = fmaf(vd, xd[i], acc[r1][i]);
                }
            }
        }
    }

#pragma unroll
    for (int r = 0; r < 4; ++r) {
        const int n = n0 + r;
        float res[4];
        if (RECUR) {
            uint2 up = *(const uint2*)(Tpp + (size_t)n * BF + fo);
            float ep[4];
            unpack4(up, ep);
#pragma unroll
            for (int i = 0; i < 4; ++i) res[i] = 2.f * acc[r][i] - ep[i];
        } else {
#pragma unroll
            for (int i = 0; i < 4; ++i) res[i] = acc[r][i];
        }
        uint2 st;
        st.x = pack2(res[0], res[1]);
        st.y = pack2(res[2], res[3]);
        *(uint2*)(Tout + (size_t)n * BF + fo) = st;
    }
}

// ---------------- FC via MFMA 16x16x32 bf16, 2 tiles/wave ----------------
__global__ __launch_bounds__(256) void fc_mfma(const ushort_t* __restrict__ X0,
                                               const ushort_t* __restrict__ T1,
                                               const ushort_t* __restrict__ T2,
                                               const ushort_t* __restrict__ T3,
                                               const ushort_t* __restrict__ T4,
                                               const ushort_t* __restrict__ T5,
                                               const ushort_t* __restrict__ Wfrag,
                                               const float* __restrict__ bias,
                                               float* __restrict__ out) {
    const int wave = threadIdx.x >> 6, lane = threadIdx.x & 63;
    const int quad = lane >> 4, col = lane & 15;
    const int tb = blockIdx.x * 128 + wave * 32;      // 2 tiles: tb, tb+16
    const int r0 = tb + col, r1 = tb + 16 + col;
    const ushort_t* Tbuf[6] = {X0, T1, T2, T3, T4, T5};

    frag_cd acc0[4], acc1[4];
#pragma unroll
    for (int ct = 0; ct < 4; ++ct) {
        acc0[ct] = (frag_cd){0.f, 0.f, 0.f, 0.f};
        acc1[ct] = (frag_cd){0.f, 0.f, 0.f, 0.f};
    }

#pragma unroll
    for (int s = 0; s < 12; ++s) {
        const int f0 = (s & 1) * 32 + quad * 8;
        frag_ab a0 = *(const frag_ab*)(Tbuf[s >> 1] + (size_t)r0 * F_ + f0);
        frag_ab a1 = *(const frag_ab*)(Tbuf[s >> 1] + (size_t)r1 * F_ + f0);
#pragma unroll
        for (int ct = 0; ct < 4; ++ct) {
            frag_ab bfr = *(const frag_ab*)(Wfrag + (((s * 4 + ct) * 64 + lane) << 3));
            acc0[ct] = __builtin_amdgcn_mfma_f32_16x16x32_bf16(a0, bfr, acc0[ct], 0, 0, 0);
            acc1[ct] = __builtin_amdgcn_mfma_f32_16x16x32_bf16(a1, bfr, acc1[ct], 0, 0, 0);
        }
    }

    // C/D: col = lane&15, row = quad*4 + reg
#pragma unroll
    for (int ct = 0; ct < 4; ++ct) {
        const int o = ct * 16 + col;
        const float bv = bias[o];
#pragma unroll
        for (int reg = 0; reg < 4; ++reg) {
            int ra = tb + quad * 4 + reg;
            int rb = ra + 16;
            out[(size_t)(ra & 7) * N_V * OUT_ + (size_t)(ra >> 3) * OUT_ + o] = acc0[ct][reg] + bv;
            out[(size_t)(rb & 7) * N_V * OUT_ + (size_t)(rb >> 3) * OUT_ + o] = acc1[ct][reg] + bv;
        }
    }
}

// ---------------- launcher ----------------

extern "C" void kernel_launch(void* const* d_in, const int* in_sizes, int n_in,
                              void* d_out, int out_size, void* d_ws, size_t ws_size,
                              hipStream_t stream) {
    const float* x    = (const float*)d_in[0];
    const int*   rows = (const int*)  d_in[1];
    const int*   cols = (const int*)  d_in[2];
    const float* vals = (const float*)d_in[3];
    const float* W    = (const float*)d_in[4];
    const float* bias = (const float*)d_in[5];
    float* out = (float*)d_out;

    const size_t TSZ = (size_t)N_V * BF;           // bf16 elements per T buffer
    ushort_t* T1 = (ushort_t*)d_ws;
    ushort_t* T2 = T1 + TSZ;
    ushort_t* T3 = T2 + TSZ;
    ushort_t* T4 = T3 + TSZ;
    ushort_t* T5 = T4 + TSZ;
    ushort_t* X0 = T5 + TSZ;
    ushort_t* Wfrag = X0 + TSZ;                    // 24576 ushorts
    int* counts    = (int*)(Wfrag + 24576);        // NBUK
    int* bp        = counts + NBUK;                // NBUK+1 (+pad)
    int* cursor    = bp + NBUK + 64;               // NBUK
    int* bsum      = cursor + NBUK;                // 256
    int2* edges    = (int2*)(bsum + 256);          // NNZ int2

    hipMemsetAsync(counts, 0, NBUK * sizeof(int), stream);
    hist_kernel<<<(NNZ_ + 255) / 256, 256, 0, stream>>>(rows, cols, counts);
    scan1<<<SCANB, 1024, 0, stream>>>(counts, cursor, bsum);
    scan2<<<1, 256, 0, stream>>>(bsum);
    scan3<<<SCANB, 1024, 0, stream>>>(counts, bsum, bp, cursor);
    scatter_kernel<<<(NNZ_ + 255) / 256, 256, 0, stream>>>(rows, cols, vals, cursor, edges);
    prep_kernel<<<20096, 256, 0, stream>>>(x, (uint_t*)X0, W, Wfrag);

    cheb_phase<false><<<N_V / 8, 256, 0, stream>>>(bp, edges, X0, nullptr, T1);
    cheb_phase<true ><<<N_V / 8, 256, 0, stream>>>(bp, edges, T1, X0, T2);
    cheb_phase<true ><<<N_V / 8, 256, 0, stream>>>(bp, edges, T2, T1, T3);
    cheb_phase<true ><<<N_V / 8, 256, 0, stream>>>(bp, edges, T3, T2, T4);
    cheb_phase<true ><<<N_V / 8, 256, 0, stream>>>(bp, edges, T4, T3, T5);

    fc_mfma<<<(N_V * B_) / 128, 256, 0, stream>>>(X0, T1, T2, T3, T4, T5, Wfrag, bias, out);
}